// Round 5
// baseline (31.010 us; speedup 1.0000x reference)
//
#include <hip/hip_runtime.h>
#include <hip/hip_bf16.h>

#define C_IN  32
#define C_OUT 64
#define HH    64
#define WW    64

typedef __attribute__((ext_vector_type(8))) short short8v;
typedef __attribute__((ext_vector_type(4))) float f32x4;

static __device__ __forceinline__ unsigned short f2bf(float f) {
    unsigned u = __builtin_bit_cast(unsigned, f);
    unsigned r = (u + 0x7FFFu + ((u >> 16) & 1u)) >> 16;   // RNE
    return (unsigned short)r;
}
static __device__ __forceinline__ float bf2f(unsigned short b) {
    unsigned u = ((unsigned)b) << 16;
    return __builtin_bit_cast(float, u);
}

// ---------------------------------------------------------------------------
// Weight-product + B-fragment pack (cold kernel, unchanged from round 4).
// W~_k = Ew(k) * (w_k if (p+k) odd), Ew(k) = prod_{j>=k, (p+j) even} w_j
// Bpk[p][part(h=0,l=1)][k(9)][octile(4)][lane(64)][j(8)]  (bf16)
//   lane = (ic>>3)*16 + (oc&15), j = ic&7, octile = oc>>4
// ---------------------------------------------------------------------------
__global__ void wprod_pack(const float* __restrict__ w, unsigned short* __restrict__ Bpk) {
    int t = blockIdx.x * 256 + threadIdx.x;
    if (t >= 2 * C_IN * C_OUT) return;
    int oc = t & 63;
    int ic = (t >> 6) & 31;
    int p  = t >> 11;
    const float* wp = w + (oc * C_IN + ic) * 9;
    float W[9];
    float Ew = 1.f;
    #pragma unroll
    for (int k = 8; k >= 0; --k) {
        float wk = wp[k];
        if (((p + k) & 1) == 0) { Ew *= wk; W[k] = Ew; }
        else                    { W[k] = wk * Ew; }
    }
    int lane = ((ic >> 3) << 4) + (oc & 15);
    int j    = ic & 7;
    int oct  = oc >> 4;
    #pragma unroll
    for (int k = 0; k < 9; ++k) {
        unsigned short hi = f2bf(W[k]);
        unsigned short lo = f2bf(W[k] - bf2f(hi));
        size_t ih = ((((size_t)(p * 2 + 0) * 9 + k) * 4 + oct) * 64 + lane) * 8 + j;
        size_t il = ((((size_t)(p * 2 + 1) * 9 + k) * 4 + oct) * 64 + lane) * 8 + j;
        Bpk[ih] = hi;
        Bpk[il] = lo;
    }
}

// ---------------------------------------------------------------------------
// GEMM body (parity compile-time). xt[a][k] -> X~ (suffix products) -> packed
// bf16 hi/lo A-frags -> 9k x 2octile x 3-term MFMA. C = Xh*Wh + Xl*Wh + Xh*Wl.
// ---------------------------------------------------------------------------
template<int P>
__device__ __forceinline__ void aeg_gemm(
    float (&xt)[8][9], const short8v* __restrict__ Bq,
    float* __restrict__ out, int n, int i0, int grp, int oh, int l)
{
    // X~: suffix products of odd-step x's; even steps multiply own x.
    #pragma unroll
    for (int a = 0; a < 8; ++a) {
        float Ox = 1.f;
        #pragma unroll
        for (int k = 8; k >= 0; --k) {
            if (((P + k) & 1) == 1) { Ox *= xt[a][k]; xt[a][k] = Ox; }
            else                    { xt[a][k] = xt[a][k] * Ox; }
        }
    }

    // Pack to bf16 hi/lo (native casts -> v_cvt_pk_bf16_f32).
    short8v ahk[9], alk[9];
    #pragma unroll
    for (int k = 0; k < 9; ++k) {
        #pragma unroll
        for (int a = 0; a < 8; ++a) {
            float v  = xt[a][k];
            __hip_bfloat16 bh = __float2bfloat16(v);
            float fh = __bfloat162float(bh);
            __hip_bfloat16 bl = __float2bfloat16(v - fh);
            ahk[k][a] = (short)__builtin_bit_cast(unsigned short, bh);
            alk[k][a] = (short)__builtin_bit_cast(unsigned short, bl);
        }
    }

    f32x4 acc[2];
    #pragma unroll
    for (int tt = 0; tt < 2; ++tt) acc[tt] = (f32x4){0.f, 0.f, 0.f, 0.f};

    const int base_h = (P * 2 + 0) * 9;
    const int base_l = (P * 2 + 1) * 9;

    #pragma unroll
    for (int k = 0; k < 9; ++k) {
        #pragma unroll
        for (int tt = 0; tt < 2; ++tt) {
            int t = oh * 2 + tt;
            short8v bh = Bq[((base_h + k) * 4 + t) * 64 + l];
            short8v bl = Bq[((base_l + k) * 4 + t) * 64 + l];
            acc[tt] = __builtin_amdgcn_mfma_f32_16x16x32_bf16(ahk[k], bh, acc[tt], 0, 0, 0);
            acc[tt] = __builtin_amdgcn_mfma_f32_16x16x32_bf16(alk[k], bh, acc[tt], 0, 0, 0);
            acc[tt] = __builtin_amdgcn_mfma_f32_16x16x32_bf16(ahk[k], bl, acc[tt], 0, 0, 0);
        }
    }

    // Scatter C: row = (l>>4)*4 + r (position), col = l&15 (oc low).
    int colc = l & 15;
    int rgrp = l >> 4;
    #pragma unroll
    for (int tt = 0; tt < 2; ++tt) {
        int oc = (oh * 2 + tt) * 16 + colc;
        #pragma unroll
        for (int r = 0; r < 4; ++r) {
            int q = grp * 16 + rgrp * 4 + r;
            int i = i0 + (q >> 5);
            int j = 2 * (q & 31) + ((i + P) & 1);
            out[(((size_t)n * C_OUT + oc) * HH + i) * WW + j] = acc[tt][r];
        }
    }
}

// ---------------------------------------------------------------------------
// Main kernel: block = 1 n x 2 rows x 64 cols x 2 octiles, 512 thr = 8 waves.
// Wave w: parity p = w&1, M-group grp = w>>1 (16 positions of that parity),
// handles octiles {2*oh, 2*oh+1} (oh from blockIdx). A-frags built in
// registers from 72 global taps (no LDS). Grid 512 = 2 blocks/CU,
// 4 waves/SIMD.
// ---------------------------------------------------------------------------
__global__ __launch_bounds__(512, 4) void aeg_mfma(
    const float* __restrict__ x, const unsigned short* __restrict__ Bpk,
    float* __restrict__ out)
{
    int bid = blockIdx.x;
    int oh  = bid & 1;         // octile pair (0..1)
    int br  = (bid >> 1) & 31; // row-block (0..31), 2 rows each
    int n   = bid >> 6;        // batch (0..7)
    int i0  = br * 2;
    int tid = threadIdx.x;
    int w   = __builtin_amdgcn_readfirstlane(tid >> 6);  // wave 0..7
    int p   = w & 1;
    int grp = w >> 1;          // 0..3
    int l   = tid & 63;

    int qA = grp * 16 + (l & 15);
    int iA = i0 + (qA >> 5);
    int jA = 2 * (qA & 31) + ((iA + p) & 1);
    int icb = (l >> 4) * 8;

    float xt[8][9];
    #pragma unroll
    for (int a = 0; a < 8; ++a) {
        const float* xb = x + ((size_t)n * C_IN + icb + a) * (HH * WW);
        #pragma unroll
        for (int di = 0; di < 3; ++di) {
            int ii = iA + di - 1;
            #pragma unroll
            for (int dj = 0; dj < 3; ++dj) {
                int jj = jA + dj - 1;
                bool ok = ((unsigned)ii < 64u) && ((unsigned)jj < 64u);
                xt[a][di * 3 + dj] = ok ? xb[ii * WW + jj] : 0.f;
            }
        }
    }

    const short8v* Bq = (const short8v*)Bpk;
    if (p == 0) aeg_gemm<0>(xt, Bq, out, n, i0, grp, oh, l);
    else        aeg_gemm<1>(xt, Bq, out, n, i0, grp, oh, l);
}

extern "C" void kernel_launch(void* const* d_in, const int* in_sizes, int n_in,
                              void* d_out, int out_size, void* d_ws, size_t ws_size,
                              hipStream_t stream) {
    const float* x = (const float*)d_in[0];
    const float* w = (const float*)d_in[1];
    float* out = (float*)d_out;
    unsigned short* Bpk = (unsigned short*)d_ws;   // 147,456 bytes

    wprod_pack<<<16, 256, 0, stream>>>(w, Bpk);
    aeg_mfma<<<512, 512, 0, stream>>>(x, Bpk, out);
}